// Round 1
// baseline (89.996 us; speedup 1.0000x reference)
//
#include <hip/hip_runtime.h>

// 5x5 local attention, B=2 H=128 W=128 C=64 BIN=64, fp32.
// Mapping: block = 256 threads = 16 pixels along W; each 16-lane group owns one
// pixel; lane within group owns a float4 of channels (C = 16*4). All global
// loads/stores are coalesced float4 (1 KiB per wave instruction).
// OOB patch entries: score 0 enters the softmax denominator (zero padding),
// value contribution skipped.

#define BB 2
#define HH 128
#define WW 128
#define CC 64
#define KK 5

__global__ __launch_bounds__(256, 4) void local_attn_kernel(
    const float* __restrict__ mainp,
    const float* __restrict__ refp,
    const float* __restrict__ refvp,
    float* __restrict__ outp)
{
    const int tid    = threadIdx.x;
    const int lane16 = tid & 15;   // channel-quad index
    const int pix    = tid >> 4;   // local pixel 0..15
    const int seg    = blockIdx.x; // 0..2047
    const int wseg   = seg & 7;
    const int h      = (seg >> 3) & (HH - 1);
    const int b      = seg >> 10;
    const int w      = wseg * 16 + pix;
    const int cb     = lane16 * 4;

    const size_t pbase = (((size_t)(b * HH + h)) * WW + w) * CC + cb;
    const float4 m4 = *reinterpret_cast<const float4*>(mainp + pbase);

    float sc[KK * KK];

    // ---- scores: per-lane partial dot over 4 channels ----
    #pragma unroll
    for (int di = 0; di < KK; ++di) {
        const int hh = h + di - 2;
        const bool hok = (unsigned)hh < (unsigned)HH;
        const float* rrow = refp + (((size_t)(b * HH + hh)) * WW + w) * CC + cb;
        #pragma unroll
        for (int dj = 0; dj < KK; ++dj) {
            const int ww = w + dj - 2;
            float p = 0.0f;
            if (hok && (unsigned)ww < (unsigned)WW) {
                const float4 r4 =
                    *reinterpret_cast<const float4*>(rrow + (dj - 2) * CC);
                p = m4.x * r4.x + m4.y * r4.y + m4.z * r4.z + m4.w * r4.w;
            }
            sc[di * KK + dj] = p;
        }
    }

    // ---- reduce each score across the 16 lanes of this pixel group ----
    #pragma unroll
    for (int p = 0; p < KK * KK; ++p) {
        float v = sc[p];
        v += __shfl_xor(v, 1);
        v += __shfl_xor(v, 2);
        v += __shfl_xor(v, 4);
        v += __shfl_xor(v, 8);
        sc[p] = v;   // now identical across the 16-lane group
    }

    // ---- softmax over 25 (OOB entries are score 0 and DO count) ----
    float mx = sc[0];
    #pragma unroll
    for (int p = 1; p < KK * KK; ++p) mx = fmaxf(mx, sc[p]);
    float s = 0.0f;
    #pragma unroll
    for (int p = 0; p < KK * KK; ++p) {
        sc[p] = __expf(sc[p] - mx);
        s += sc[p];
    }
    const float inv = 1.0f / s;

    // ---- attention-weighted value sum (lane owns 4 of the 64 bins) ----
    float4 acc = make_float4(0.f, 0.f, 0.f, 0.f);
    #pragma unroll
    for (int di = 0; di < KK; ++di) {
        const int hh = h + di - 2;
        const bool hok = (unsigned)hh < (unsigned)HH;
        const float* vrow = refvp + (((size_t)(b * HH + hh)) * WW + w) * CC + cb;
        #pragma unroll
        for (int dj = 0; dj < KK; ++dj) {
            const int ww = w + dj - 2;
            if (hok && (unsigned)ww < (unsigned)WW) {
                const float4 v4 =
                    *reinterpret_cast<const float4*>(vrow + (dj - 2) * CC);
                const float a = sc[di * KK + dj];
                acc.x += a * v4.x;
                acc.y += a * v4.y;
                acc.z += a * v4.z;
                acc.w += a * v4.w;
            }
        }
    }
    acc.x *= inv; acc.y *= inv; acc.z *= inv; acc.w *= inv;

    *reinterpret_cast<float4*>(outp + pbase) = acc;
}

extern "C" void kernel_launch(void* const* d_in, const int* in_sizes, int n_in,
                              void* d_out, int out_size, void* d_ws, size_t ws_size,
                              hipStream_t stream) {
    const float* mainp = (const float*)d_in[0];
    const float* refp  = (const float*)d_in[1];
    const float* refvp = (const float*)d_in[2];
    float* outp        = (float*)d_out;

    const int blocks = BB * HH * (WW / 16);  // 2048
    local_attn_kernel<<<blocks, 256, 0, stream>>>(mainp, refp, refvp, outp);
}

// Round 2
// 84.401 us; speedup vs baseline: 1.0663x; 1.0663x over previous
//
#include <hip/hip_runtime.h>

// 5x5 local attention, B=2 H=128 W=128 C=64 BIN=64, fp32.
// Mapping: block = 256 threads = 16 pixels along W; each 16-lane group owns one
// pixel; lane owns a float4 of channels (C = 16*4). All global loads/stores
// are coalesced float4 (1 KiB per wave instruction).
//
// R2 changes vs R1:
//  - 16-lane score reduction via DPP (quad_perm xor1/xor2 + row_ror 4/8) on
//    the VALU pipe instead of 100 ds_swizzle ops on the LDS pipe.
//  - Branch-free boundary handling: clamped addresses + cndmask zeroing.
//    OOB entries keep score 0 in the softmax denominator (zero padding), and
//    get weight 0 in the value sum — exact reference semantics.

#define BB 2
#define HH 128
#define WW 128
#define CC 64
#define KK 5

template <int CTRL>
__device__ __forceinline__ float dpp_add(float v) {
    int r = __builtin_amdgcn_update_dpp(0, __float_as_int(v), CTRL, 0xF, 0xF, true);
    return v + __int_as_float(r);
}

// Sum across the 16 lanes of a DPP row (== one pixel group; lanes consecutive).
__device__ __forceinline__ float group16_sum(float v) {
    v = dpp_add<0xB1>(v);    // quad_perm(1,0,3,2) : xor 1
    v = dpp_add<0x4E>(v);    // quad_perm(2,3,0,1) : xor 2
    v = dpp_add<0x124>(v);   // row_ror:4  (pairs quads across distance 4)
    v = dpp_add<0x128>(v);   // row_ror:8  (pairs halves of the 16-row)
    return v;
}

__global__ __launch_bounds__(256, 4) void local_attn_kernel(
    const float* __restrict__ mainp,
    const float* __restrict__ refp,
    const float* __restrict__ refvp,
    float* __restrict__ outp)
{
    const int tid    = threadIdx.x;
    const int lane16 = tid & 15;   // channel-quad index
    const int pix    = tid >> 4;   // local pixel 0..15
    const int seg    = blockIdx.x; // 0..2047
    const int wseg   = seg & 7;
    const int h      = (seg >> 3) & (HH - 1);   // uniform per block
    const int b      = seg >> 10;
    const int w      = wseg * 16 + pix;
    const int cb     = lane16 * 4;

    const size_t pbase = (((size_t)(b * HH + h)) * WW + w) * CC + cb;
    const float4 m4 = *reinterpret_cast<const float4*>(mainp + pbase);

    float sc[KK * KK];

    // ---- scores: branch-free clamped loads, per-lane partial dot ----
    #pragma unroll
    for (int di = 0; di < KK; ++di) {
        const int hh  = h + di - 2;
        const int hhc = min(max(hh, 0), HH - 1);        // scalar (h uniform)
        const float* rrow = refp + ((size_t)(b * HH + hhc) * WW) * CC + cb;
        #pragma unroll
        for (int dj = 0; dj < KK; ++dj) {
            const int ww  = w + dj - 2;
            const int wwc = min(max(ww, 0), WW - 1);
            const float4 r4 =
                *reinterpret_cast<const float4*>(rrow + (size_t)wwc * CC);
            const bool ok = ((unsigned)hh < (unsigned)HH) &
                            ((unsigned)ww < (unsigned)WW);
            const float p = m4.x * r4.x + m4.y * r4.y + m4.z * r4.z + m4.w * r4.w;
            sc[di * KK + dj] = ok ? p : 0.0f;
        }
    }

    // ---- reduce each score across the 16-lane group (VALU/DPP, no LDS pipe) ----
    #pragma unroll
    for (int p = 0; p < KK * KK; ++p) sc[p] = group16_sum(sc[p]);

    // ---- softmax over 25 (OOB entries are score 0 and DO count) ----
    float mx = sc[0];
    #pragma unroll
    for (int p = 1; p < KK * KK; ++p) mx = fmaxf(mx, sc[p]);
    float s = 0.0f;
    #pragma unroll
    for (int p = 0; p < KK * KK; ++p) { sc[p] = __expf(sc[p] - mx); s += sc[p]; }
    const float inv = 1.0f / s;
    #pragma unroll
    for (int p = 0; p < KK * KK; ++p) sc[p] *= inv;

    // ---- value accumulation: branch-free, OOB weight forced to 0 ----
    float4 acc = make_float4(0.f, 0.f, 0.f, 0.f);
    #pragma unroll
    for (int di = 0; di < KK; ++di) {
        const int hh  = h + di - 2;
        const int hhc = min(max(hh, 0), HH - 1);
        const float* vrow = refvp + ((size_t)(b * HH + hhc) * WW) * CC + cb;
        #pragma unroll
        for (int dj = 0; dj < KK; ++dj) {
            const int ww  = w + dj - 2;
            const int wwc = min(max(ww, 0), WW - 1);
            const float4 v4 =
                *reinterpret_cast<const float4*>(vrow + (size_t)wwc * CC);
            const bool ok = ((unsigned)hh < (unsigned)HH) &
                            ((unsigned)ww < (unsigned)WW);
            const float a = ok ? sc[di * KK + dj] : 0.0f;
            acc.x += a * v4.x;
            acc.y += a * v4.y;
            acc.z += a * v4.z;
            acc.w += a * v4.w;
        }
    }

    *reinterpret_cast<float4*>(outp + pbase) = acc;
}

extern "C" void kernel_launch(void* const* d_in, const int* in_sizes, int n_in,
                              void* d_out, int out_size, void* d_ws, size_t ws_size,
                              hipStream_t stream) {
    const float* mainp = (const float*)d_in[0];
    const float* refp  = (const float*)d_in[1];
    const float* refvp = (const float*)d_in[2];
    float* outp        = (float*)d_out;

    const int blocks = BB * HH * (WW / 16);  // 2048
    local_attn_kernel<<<blocks, 256, 0, stream>>>(mainp, refp, refvp, outp);
}

// Round 3
// 82.893 us; speedup vs baseline: 1.0857x; 1.0182x over previous
//
#include <hip/hip_runtime.h>

// 5x5 local attention, B=2 H=128 W=128 C=64 BIN=64, fp32.
//
// R3: zero-padded LDS tile (5 rows x 20 cols x 64 ch = 25.6 KB), staged once
// per operand (buffer reused ref -> ref_value, 3 barriers, 6 blocks/CU).
// All 25+25 inner reads are ds_read_b128 with immediate offsets off one base
// register — no clamps, no cndmask, no per-load 64-bit address math.
// Zero padding makes OOB semantics exact: padded score = 0 participates in
// the softmax denominator, padded value contributes 0.
// Block = 256 threads = 16 pixels; 16-lane group per pixel; lane owns 4 ch.
// Score reduction across the 16-lane group via DPP on the VALU pipe.

#define BB 2
#define HH 128
#define WW 128
#define CC 64
#define KK 5
#define PAD 2
#define TC 20            // tile cols = 16 + 2*PAD
#define NV (KK * TC)     // 100 column-vectors per tile

template <int CTRL>
__device__ __forceinline__ float dpp_add(float v) {
    int r = __builtin_amdgcn_update_dpp(0, __float_as_int(v), CTRL, 0xF, 0xF, true);
    return v + __int_as_float(r);
}

// Sum across the 16 lanes of a DPP row (== one pixel group).
__device__ __forceinline__ float group16_sum(float v) {
    v = dpp_add<0xB1>(v);    // quad_perm xor 1
    v = dpp_add<0x4E>(v);    // quad_perm xor 2
    v = dpp_add<0x124>(v);   // row_ror:4
    v = dpp_add<0x128>(v);   // row_ror:8
    return v;
}

// Stage one zero-padded [KK x TC x CC] tile into LDS. grp = tid>>4 picks the
// column-vector; lane16 covers the 64 channels as float4.
__device__ __forceinline__ void stage_tile(const float* __restrict__ src,
                                           float* __restrict__ lds,
                                           int b, int h, int w0,
                                           int grp, int lane16) {
    #pragma unroll
    for (int i = 0; i < 7; ++i) {
        const int v = grp + 16 * i;
        if (v < NV) {
            const int r   = v / TC;
            const int c   = v - r * TC;
            const int hg  = h + r - PAD;
            const int wg  = w0 + c - PAD;
            const int hgc = min(max(hg, 0), HH - 1);
            const int wgc = min(max(wg, 0), WW - 1);
            const float4 d = *reinterpret_cast<const float4*>(
                src + (((size_t)(b * HH + hgc)) * WW + wgc) * CC + lane16 * 4);
            const bool ok = ((unsigned)hg < (unsigned)HH) &
                            ((unsigned)wg < (unsigned)WW);
            float4 z;
            z.x = ok ? d.x : 0.0f;
            z.y = ok ? d.y : 0.0f;
            z.z = ok ? d.z : 0.0f;
            z.w = ok ? d.w : 0.0f;
            *reinterpret_cast<float4*>(lds + (size_t)v * CC + lane16 * 4) = z;
        }
    }
}

__global__ __launch_bounds__(256, 4) void local_attn_kernel(
    const float* __restrict__ mainp,
    const float* __restrict__ refp,
    const float* __restrict__ refvp,
    float* __restrict__ outp)
{
    __shared__ float tile[NV * CC];   // 25.6 KB, reused ref -> ref_value

    const int tid    = threadIdx.x;
    const int lane16 = tid & 15;      // channel-quad index
    const int pix    = tid >> 4;      // local pixel 0..15
    const int seg    = blockIdx.x;    // 0..2047
    const int wseg   = seg & 7;
    const int h      = (seg >> 3) & (HH - 1);   // uniform per block
    const int b      = seg >> 10;
    const int w0     = wseg * 16;
    const int w      = w0 + pix;
    const int cb     = lane16 * 4;

    const size_t pbase = (((size_t)(b * HH + h)) * WW + w) * CC + cb;
    const float4 m4 = *reinterpret_cast<const float4*>(mainp + pbase);

    // ---- phase 1: stage ref tile ----
    stage_tile(refp, tile, b, h, w0, pix, lane16);
    __syncthreads();

    // Pixel pix sees tile cols pix+dj (dj=0..4 <-> offsets -2..+2).
    const float* tbase = tile + (size_t)pix * CC + cb;

    // ---- scores: 25 ds_read_b128 with immediate offsets ----
    float sc[KK * KK];
    #pragma unroll
    for (int r = 0; r < KK; ++r) {
        #pragma unroll
        for (int dj = 0; dj < KK; ++dj) {
            const float4 t =
                *reinterpret_cast<const float4*>(tbase + (r * TC + dj) * CC);
            sc[r * KK + dj] = m4.x * t.x + m4.y * t.y + m4.z * t.z + m4.w * t.w;
        }
    }

    // ---- reduce each score across the 16-lane group (VALU/DPP) ----
    #pragma unroll
    for (int p = 0; p < KK * KK; ++p) sc[p] = group16_sum(sc[p]);

    // ---- softmax over 25 (padded entries are exactly 0 and count) ----
    float mx = sc[0];
    #pragma unroll
    for (int p = 1; p < KK * KK; ++p) mx = fmaxf(mx, sc[p]);
    float s = 0.0f;
    #pragma unroll
    for (int p = 0; p < KK * KK; ++p) { sc[p] = __expf(sc[p] - mx); s += sc[p]; }
    const float inv = 1.0f / s;
    #pragma unroll
    for (int p = 0; p < KK * KK; ++p) sc[p] *= inv;

    // ---- phase 2: restage tile with ref_value ----
    __syncthreads();                  // all reads of ref tile done
    stage_tile(refvp, tile, b, h, w0, pix, lane16);
    __syncthreads();

    // ---- value accumulation: 25 ds_read_b128, weights from registers ----
    float4 acc = make_float4(0.f, 0.f, 0.f, 0.f);
    #pragma unroll
    for (int r = 0; r < KK; ++r) {
        #pragma unroll
        for (int dj = 0; dj < KK; ++dj) {
            const float4 t =
                *reinterpret_cast<const float4*>(tbase + (r * TC + dj) * CC);
            const float a = sc[r * KK + dj];
            acc.x += a * t.x;
            acc.y += a * t.y;
            acc.z += a * t.z;
            acc.w += a * t.w;
        }
    }

    *reinterpret_cast<float4*>(outp + pbase) = acc;
}

extern "C" void kernel_launch(void* const* d_in, const int* in_sizes, int n_in,
                              void* d_out, int out_size, void* d_ws, size_t ws_size,
                              hipStream_t stream) {
    const float* mainp = (const float*)d_in[0];
    const float* refp  = (const float*)d_in[1];
    const float* refvp = (const float*)d_in[2];
    float* outp        = (float*)d_out;

    const int blocks = BB * HH * (WW / 16);  // 2048
    local_attn_kernel<<<blocks, 256, 0, stream>>>(mainp, refp, refvp, outp);
}

// Round 4
// 82.684 us; speedup vs baseline: 1.0884x; 1.0025x over previous
//
#include <hip/hip_runtime.h>

// 5x5 local attention, B=2 H=128 W=128 C=64 BIN=64, fp32.
//
// R4: split the two read streams across pipes + interior specialization.
//  - Scores: zero-padded ref tile in LDS (25.6 KB), 25 ds_read_b128/wave.
//  - Values: read straight from global (L1/L2) — runs on the VMEM pipe in
//    parallel with the LDS pipe across resident blocks. Interior blocks
//    (72.7%) use pure affine addresses: 5 row bases + immediate offsets,
//    no clamps, no masks. Edge blocks keep clamped addresses + weight masks.
//  - Single __syncthreads; staging index via incremental wrap (no int div).
// Semantics: zero-padded tile => OOB score = 0 enters softmax denominator;
// OOB value weight forced to 0 (edge path) — exact reference behavior.
// Block = 256 threads = 16 pixels; 16-lane group per pixel; lane owns 4 ch;
// score reduction via DPP on the VALU pipe.

#define BB 2
#define HH 128
#define WW 128
#define CC 64
#define KK 5
#define PAD 2
#define TC 20            // tile cols = 16 + 2*PAD
#define NV (KK * TC)     // 100 column-vectors per tile

template <int CTRL>
__device__ __forceinline__ float dpp_add(float v) {
    int r = __builtin_amdgcn_update_dpp(0, __float_as_int(v), CTRL, 0xF, 0xF, true);
    return v + __int_as_float(r);
}

// Sum across the 16 lanes of a DPP row (== one pixel group).
__device__ __forceinline__ float group16_sum(float v) {
    v = dpp_add<0xB1>(v);    // quad_perm xor 1
    v = dpp_add<0x4E>(v);    // quad_perm xor 2
    v = dpp_add<0x124>(v);   // row_ror:4
    v = dpp_add<0x128>(v);   // row_ror:8
    return v;
}

__global__ __launch_bounds__(256, 4) void local_attn_kernel(
    const float* __restrict__ mainp,
    const float* __restrict__ refp,
    const float* __restrict__ refvp,
    float* __restrict__ outp)
{
    __shared__ float reft[NV * CC];   // 25.6 KB zero-padded ref tile

    const int tid    = threadIdx.x;
    const int lane16 = tid & 15;      // channel-quad index
    const int pix    = tid >> 4;      // local pixel 0..15
    const int seg    = blockIdx.x;    // 0..2047
    const int wseg   = seg & 7;
    const int h      = (seg >> 3) & (HH - 1);   // uniform per block
    const int b      = seg >> 10;
    const int w0     = wseg * 16;
    const int w      = w0 + pix;
    const int cb     = lane16 * 4;

    const size_t pbase = (((size_t)(b * HH + h)) * WW + w) * CC + cb;
    const float4 m4 = *reinterpret_cast<const float4*>(mainp + pbase);

    const bool interior = (wseg >= 1) & (wseg <= 6) & (h >= PAD) & (h < HH - PAD);

    // ---- stage zero-padded ref tile: vector v=(r,c) -> reft[v*CC] ----
    // Thread (pix, lane16) stages channel-quad cb of vectors v = pix + 16*i.
    {
        int r = 0, c = pix;            // v = pix, then v += 16 with wrap
        if (interior) {
            const float* srcb =
                refp + (((size_t)(b * HH + h - PAD)) * WW + (w0 - PAD)) * CC + cb;
            #pragma unroll
            for (int i = 0; i < 7; ++i) {
                const int v = pix + 16 * i;
                if (v < NV) {
                    const float4 d = *reinterpret_cast<const float4*>(
                        srcb + ((size_t)(r * WW + c)) * CC);
                    *reinterpret_cast<float4*>(reft + (size_t)v * CC + cb) = d;
                }
                c += 16; const bool wr = (c >= TC); c = wr ? c - TC : c; r += wr;
            }
        } else {
            #pragma unroll
            for (int i = 0; i < 7; ++i) {
                const int v = pix + 16 * i;
                if (v < NV) {
                    const int hg  = h + r - PAD;
                    const int wg  = w0 + c - PAD;
                    const int hgc = min(max(hg, 0), HH - 1);
                    const int wgc = min(max(wg, 0), WW - 1);
                    const float4 d = *reinterpret_cast<const float4*>(
                        refp + (((size_t)(b * HH + hgc)) * WW + wgc) * CC + cb);
                    const bool ok = ((unsigned)hg < (unsigned)HH) &
                                    ((unsigned)wg < (unsigned)WW);
                    float4 z;
                    z.x = ok ? d.x : 0.0f;
                    z.y = ok ? d.y : 0.0f;
                    z.z = ok ? d.z : 0.0f;
                    z.w = ok ? d.w : 0.0f;
                    *reinterpret_cast<float4*>(reft + (size_t)v * CC + cb) = z;
                }
                c += 16; const bool wr = (c >= TC); c = wr ? c - TC : c; r += wr;
            }
        }
    }
    __syncthreads();

    // ---- scores: 25 ds_read_b128 with immediate offsets ----
    const float* tbase = reft + pix * CC + cb;
    float sc[KK * KK];
    #pragma unroll
    for (int r = 0; r < KK; ++r) {
        #pragma unroll
        for (int dj = 0; dj < KK; ++dj) {
            const float4 t =
                *reinterpret_cast<const float4*>(tbase + (r * TC + dj) * CC);
            sc[r * KK + dj] = m4.x * t.x + m4.y * t.y + m4.z * t.z + m4.w * t.w;
        }
    }

    // ---- reduce each score across the 16-lane group (VALU/DPP) ----
    #pragma unroll
    for (int p = 0; p < KK * KK; ++p) sc[p] = group16_sum(sc[p]);

    // ---- softmax over 25 (padded entries exactly 0, included) ----
    float mx = sc[0];
    #pragma unroll
    for (int p = 1; p < KK * KK; ++p) mx = fmaxf(mx, sc[p]);
    float ssum = 0.0f;
    #pragma unroll
    for (int p = 0; p < KK * KK; ++p) { sc[p] = __expf(sc[p] - mx); ssum += sc[p]; }
    const float inv = 1.0f / ssum;     // applied to acc at the end

    // ---- values from GLOBAL (VMEM pipe, parallel to LDS pipe) ----
    float4 acc = make_float4(0.f, 0.f, 0.f, 0.f);
    if (interior) {
        const float* vb = refvp + pbase;
        #pragma unroll
        for (int di = 0; di < KK; ++di) {
            const float* row = vb + (ptrdiff_t)(di - PAD) * (WW * CC);
            #pragma unroll
            for (int dj = 0; dj < KK; ++dj) {
                const float4 v4 =
                    *reinterpret_cast<const float4*>(row + (dj - PAD) * CC);
                const float a = sc[di * KK + dj];
                acc.x += a * v4.x;
                acc.y += a * v4.y;
                acc.z += a * v4.z;
                acc.w += a * v4.w;
            }
        }
    } else {
        int   wwc[KK];
        float wokf[KK];
        #pragma unroll
        for (int dj = 0; dj < KK; ++dj) {
            const int ww_ = w + dj - PAD;
            wwc[dj]  = min(max(ww_, 0), WW - 1);
            wokf[dj] = ((unsigned)ww_ < (unsigned)WW) ? 1.0f : 0.0f;
        }
        #pragma unroll
        for (int di = 0; di < KK; ++di) {
            const int hh_  = h + di - PAD;
            const int hhc  = min(max(hh_, 0), HH - 1);
            const float hokf = ((unsigned)hh_ < (unsigned)HH) ? 1.0f : 0.0f;
            const float* row = refvp + (((size_t)(b * HH + hhc)) * WW) * CC + cb;
            #pragma unroll
            for (int dj = 0; dj < KK; ++dj) {
                const float4 v4 =
                    *reinterpret_cast<const float4*>(row + (size_t)wwc[dj] * CC);
                const float a = sc[di * KK + dj] * hokf * wokf[dj];
                acc.x += a * v4.x;
                acc.y += a * v4.y;
                acc.z += a * v4.z;
                acc.w += a * v4.w;
            }
        }
    }
    acc.x *= inv; acc.y *= inv; acc.z *= inv; acc.w *= inv;

    *reinterpret_cast<float4*>(outp + pbase) = acc;
}

extern "C" void kernel_launch(void* const* d_in, const int* in_sizes, int n_in,
                              void* d_out, int out_size, void* d_ws, size_t ws_size,
                              hipStream_t stream) {
    const float* mainp = (const float*)d_in[0];
    const float* refp  = (const float*)d_in[1];
    const float* refvp = (const float*)d_in[2];
    float* outp        = (float*)d_out;

    const int blocks = BB * HH * (WW / 16);  // 2048
    local_attn_kernel<<<blocks, 256, 0, stream>>>(mainp, refp, refvp, outp);
}